// Round 9
// baseline (119.332 us; speedup 1.0000x reference)
//
#include <hip/hip_runtime.h>
#include <hip/hip_bf16.h>

#define B_   32
#define C_   128
#define L_   4096
#define P_   100
#define NPT  7            // p-tiles of 16 (P padded to 112)
#define Q_   20
#define NBIN 21
#define NCH  (NPT * 4)    // 28 A-frag chunks; chunk = pt*4 + ks
#define HSZ  (P_ * NBIN)  // ints per block histogram (2100)

typedef short          bf16x8 __attribute__((ext_vector_type(8)));
typedef float          f32x4  __attribute__((ext_vector_type(4)));
typedef unsigned short u16x8  __attribute__((ext_vector_type(8)));

// threshold tables (filled by prep_kernel block 7)
__device__ float mn_c[P_];
__device__ float invd_c[P_];

__device__ inline unsigned short f2bf(float f) {
    __hip_bfloat16 h = __float2bfloat16(f);   // RNE
    unsigned short u; __builtin_memcpy(&u, &h, 2);
    return u;
}

// ---- prep (one dispatch): blocks 0..6 pack W -> bf16 A-frag lane order in d_ws,
// block 7 computes thresholds. Wf[chunk][lane][j], chunk=pt*4+ks:
// value = W[pt*16+(lane&15)][ks*32+(lane>>4)*8+j] (rows p>=100 zeroed).
__global__ void prep_kernel(const float* __restrict__ W, const float* __restrict__ minv,
                            const float* __restrict__ maxv, unsigned short* __restrict__ Wf) {
    const int t = blockIdx.x * 256 + threadIdx.x;
    if (t < NCH * 64) {
        const int chunk = t >> 6, lane = t & 63;
        const int pt = chunk >> 2, ks = chunk & 3;
        const int p  = pt * 16 + (lane & 15);
        const int c0 = ks * 32 + (lane >> 4) * 8;
        u16x8 v;
#pragma unroll
        for (int j = 0; j < 8; ++j)
            v[j] = (p < P_) ? f2bf(W[p * C_ + c0 + j]) : (unsigned short)0;
        *(u16x8*)(Wf + (size_t)t * 8) = v;
    } else if (t >= NCH * 64 && t < NCH * 64 + P_) {
        const int p = t - NCH * 64;
        const float mn = minv[p];
        mn_c[p]   = mn;
        invd_c[p] = (float)NBIN / (maxv[p] - mn);
    }
}

// ---- main: block = (b, 128-l chunk), 4 waves; wave owns 32 l (2 l-tiles).
// R9 change: X staged to LDS via global_load_lds width=16 (no dest VGPRs ->
// compiler CANNOT chunk the loads; all 16 DMA insts stay in flight, one drain
// at the barrier -- attacks R4-R8's serialized-latency floor). LDS layout
// [c][l]: rows of 128 floats (512B); DMA inst i of wave w moves rows c0=w*32+2i
// and c0+1 (lanes 0-31 -> row c0, lanes 32-63 -> c0+1), dest = uniform base +
// lane*16 (m104-compliant, no padding). A-frags read straight from global Wf
// (28 KB, L1-resident). C/D: col=lane&15, row=quad*4+reg [m89-verified].
// Epilogue = R6's direct atomic path (R8 falsified atomic-contention theory).
__global__ __launch_bounds__(256, 2)
void radon_dma_kernel(const float* __restrict__ X, const unsigned short* __restrict__ Wf,
                      float* __restrict__ out) {
    __shared__ float Xlds[C_ * 128];   // 64 KB, [c][l-local], 512B rows
    __shared__ int   hist[HSZ];        // 8.4 KB

    const int tid  = threadIdx.x;
    const int b    = blockIdx.y;
    const int lblk = blockIdx.x;       // 0..31
    const int wave = tid >> 6;
    const int lane = tid & 63;
    const int quad = lane >> 4;
    const int nn   = lane & 15;

    // ---- Phase A: issue X DMA (16 insts, zero VGPR results) + hist zero + barrier
    {
        const float* gb = X + ((size_t)b * C_ + (lane >> 5)) * L_ + lblk * 128 + (lane & 31) * 4;
#pragma unroll
        for (int i = 0; i < 16; ++i) {
            const int c0 = wave * 32 + i * 2;
            __builtin_amdgcn_global_load_lds(
                (const __attribute__((address_space(1))) unsigned int*)(gb + (size_t)c0 * L_),
                (__attribute__((address_space(3))) unsigned int*)&Xlds[c0 * 128],
                16, 0, 0);
        }
    }
    for (int i = tid; i < HSZ; i += 256) hist[i] = 0;
    __syncthreads();   // drains DMA (vmcnt) + hist zero (lgkm)

    // ---- Phase B: build bf16 B-frags from LDS (ds_read_b32, 4-way alias ~1.6x)
    // B[k=quad*8+j][n=lane&15], l-local = wave*32 + lt*16 + nn
    bf16x8 bfrag[2][4];
#pragma unroll
    for (int lt = 0; lt < 2; ++lt) {
        const int ll = wave * 32 + lt * 16 + nn;
#pragma unroll
        for (int ks = 0; ks < 4; ++ks) {
            float xf[8];
#pragma unroll
            for (int j = 0; j < 8; ++j)
                xf[j] = Xlds[(ks * 32 + quad * 8 + j) * 128 + ll];
            unsigned int u[4];
#pragma unroll
            for (int jp = 0; jp < 4; ++jp) {
                __hip_bfloat162 h2 = __float22bfloat162_rn(
                    make_float2(xf[2 * jp], xf[2 * jp + 1]));
                __builtin_memcpy(&u[jp], &h2, 4);
            }
            __builtin_memcpy(&bfrag[lt][ks], u, 16);
        }
    }

    // ---- Phase C: 7 p-tiles; A-frags from global Wf (coalesced dwordx4, L1-hot)
    for (int pt = 0; pt < NPT; ++pt) {
        bf16x8 afrag[4];
#pragma unroll
        for (int ks = 0; ks < 4; ++ks)
            afrag[ks] = *(const bf16x8*)(Wf + ((size_t)(pt * 4 + ks) * 64 + lane) * 8);

        f32x4 acc0 = {0.f, 0.f, 0.f, 0.f};
        f32x4 acc1 = {0.f, 0.f, 0.f, 0.f};
#pragma unroll
        for (int ks = 0; ks < 4; ++ks) {
            acc0 = __builtin_amdgcn_mfma_f32_16x16x32_bf16(afrag[ks], bfrag[0][ks], acc0, 0, 0, 0);
            acc1 = __builtin_amdgcn_mfma_f32_16x16x32_bf16(afrag[ks], bfrag[1][ks], acc1, 0, 0, 0);
        }

        // D row = quad*4 + r -> p = pt*16 + quad*4 + r (skip pad rows)
#pragma unroll
        for (int r = 0; r < 4; ++r) {
            const int p = pt * 16 + quad * 4 + r;
            if (p < P_) {
                const float mn   = mn_c[p];
                const float invd = invd_c[p];
                {
                    const float t = (acc0[r] - mn) * invd;
                    int k = 0;
                    if (t > 0.f) { const int ki = (int)t; k = (ki > 20) ? 20 : ki; }
                    atomicAdd(&hist[p * NBIN + k], 1);
                }
                {
                    const float t = (acc1[r] - mn) * invd;
                    int k = 0;
                    if (t > 0.f) { const int ki = (int)t; k = (ki > 20) ? 20 : ki; }
                    atomicAdd(&hist[p * NBIN + k], 1);
                }
            }
        }
    }
    __syncthreads();

    // ---- Phase D: prefix-sum histogram -> exact fp32 atomic accumulation
    // (counts <= 4096, scale 2^-12: every partial sum exact in fp32)
    for (int i = tid; i < P_ * Q_; i += 256) {
        const int p  = i / Q_;
        const int qi = i - p * Q_;
        int s = 0;
        for (int k = 0; k <= qi; ++k) s += hist[p * NBIN + k];
        atomicAdd(&out[((size_t)b * P_ + p) * Q_ + qi], (float)s * (1.0f / (float)L_));
    }
}

extern "C" void kernel_launch(void* const* d_in, const int* in_sizes, int n_in,
                              void* d_out, int out_size, void* d_ws, size_t ws_size,
                              hipStream_t stream) {
    const float* X  = (const float*)d_in[0];
    const float* W  = (const float*)d_in[1];
    const float* mn = (const float*)d_in[2];
    const float* mx = (const float*)d_in[3];
    float* out = (float*)d_out;
    unsigned short* Wf = (unsigned short*)d_ws;   // 28672 B

    hipMemsetAsync(out, 0, (size_t)out_size * sizeof(float), stream);
    prep_kernel<<<8, 256, 0, stream>>>(W, mn, mx, Wf);

    dim3 grid(L_ / 128, B_);
    radon_dma_kernel<<<grid, dim3(256), 0, stream>>>(X, Wf, out);
}

// Round 10
// 117.680 us; speedup vs baseline: 1.0140x; 1.0140x over previous
//
#include <hip/hip_runtime.h>
#include <hip/hip_bf16.h>

#define B_   32
#define C_   128
#define L_   4096
#define P_   100
#define NPT  7            // p-tiles of 16 (P padded to 112)
#define Q_   20
#define NBIN 21
#define NCH  (NPT * 4)    // 28 A-frag chunks; chunk = pt*4 + ks
#define HSZ  (P_ * NBIN)  // ints per block histogram (2100)
#define LT_  256          // l per block
#define TPB  512          // threads per block (8 waves)

typedef short          bf16x8 __attribute__((ext_vector_type(8)));
typedef float          f32x4  __attribute__((ext_vector_type(4)));
typedef unsigned short u16x8  __attribute__((ext_vector_type(8)));

// threshold tables (filled by prep_kernel block 7)
__device__ float mn_c[P_];
__device__ float invd_c[P_];

__device__ inline unsigned short f2bf(float f) {
    __hip_bfloat16 h = __float2bfloat16(f);   // RNE
    unsigned short u; __builtin_memcpy(&u, &h, 2);
    return u;
}

// ---- prep (one dispatch): blocks 0..6 pack W -> bf16 A-frag lane order in d_ws,
// block 7 computes thresholds. Wf[chunk][lane][j], chunk=pt*4+ks:
// value = W[pt*16+(lane&15)][ks*32+(lane>>4)*8+j] (rows p>=100 zeroed).
__global__ void prep_kernel(const float* __restrict__ W, const float* __restrict__ minv,
                            const float* __restrict__ maxv, unsigned short* __restrict__ Wf) {
    const int t = blockIdx.x * 256 + threadIdx.x;
    if (t < NCH * 64) {
        const int chunk = t >> 6, lane = t & 63;
        const int pt = chunk >> 2, ks = chunk & 3;
        const int p  = pt * 16 + (lane & 15);
        const int c0 = ks * 32 + (lane >> 4) * 8;
        u16x8 v;
#pragma unroll
        for (int j = 0; j < 8; ++j)
            v[j] = (p < P_) ? f2bf(W[p * C_ + c0 + j]) : (unsigned short)0;
        *(u16x8*)(Wf + (size_t)t * 8) = v;
    } else if (t >= NCH * 64 && t < NCH * 64 + P_) {
        const int p = t - NCH * 64;
        const float mn = minv[p];
        mn_c[p]   = mn;
        invd_c[p] = (float)NBIN / (maxv[p] - mn);
    }
}

// ---- main: block = (b, 256-l chunk), 8 waves; wave owns 32 l (2 l-tiles).
// R10: c-dimension SOFTWARE PIPELINE through __syncthreads (R9 post-mortem:
// monolithic load->barrier->compute phases convoy across co-resident blocks;
// load and compute never overlap). X is staged per 32-c QUARTER (32 KB) into
// a rotating 2-buffer LDS; iteration ks issues DMA(ks+1 -> other buf), computes
// MFMAs on quarter ks, then barriers -- the barrier's mandatory vmcnt(0) drain
// sits AFTER compute, so DMA(ks+1) had the whole compute phase to fly.
//   DMA: inst (wave w, i): c_local = w*4+i; src lane = X[b][ks*32+c_local][l0+lane*4]
//        dest = uniform base + lane*16 (m104-compliant, rows contiguous).
//   B-frag (X, LDS):  B[k=quad*8+j][n=lane&15], ll = wave*32+lt*16+nn.
//   A-frag (W): straight from pre-arranged global Wf (28 KB, L1-hot).
//   C/D: col=lane&15, row=quad*4+reg [m89-verified]. acc[7][2] persists across
//   quarters (56 VGPRs). Bucket: uniform 21-bin LDS histogram; prefix-sum
//   epilogue, exact fp32 atomicAdd (multiples of 2^-12, counts<=4096).
__global__ __launch_bounds__(TPB, 4)
void radon_pipe_kernel(const float* __restrict__ X, const unsigned short* __restrict__ Wf,
                       float* __restrict__ out) {
    __shared__ __align__(16) float Xb0[32 * LT_];   // 32 KB
    __shared__ __align__(16) float Xb1[32 * LT_];   // 32 KB
    __shared__ int hist[HSZ];                       // 8.4 KB

    const int tid  = threadIdx.x;
    const int b    = blockIdx.y;
    const int lblk = blockIdx.x;       // 0..15
    const int wave = tid >> 6;         // 0..7
    const int lane = tid & 63;
    const int quad = lane >> 4;
    const int nn   = lane & 15;

    const float* gsrc = X + (size_t)b * C_ * L_ + lblk * LT_ + lane * 4;

#define ISSUE_Q(KS, DST) do {                                                        \
    const float* s_ = gsrc + (size_t)((KS) * 32 + wave * 4) * L_;                    \
    float* d_ = (DST) + (wave * 4) * LT_;                                            \
    _Pragma("unroll")                                                                \
    for (int i_ = 0; i_ < 4; ++i_)                                                   \
        __builtin_amdgcn_global_load_lds(                                            \
            (const __attribute__((address_space(1))) unsigned int*)(s_ + (size_t)i_ * L_), \
            (__attribute__((address_space(3))) unsigned int*)(d_ + i_ * LT_),        \
            16, 0, 0);                                                               \
} while (0)

    f32x4 acc[NPT][2];
#pragma unroll
    for (int pt = 0; pt < NPT; ++pt) {
        acc[pt][0] = (f32x4){0.f, 0.f, 0.f, 0.f};
        acc[pt][1] = (f32x4){0.f, 0.f, 0.f, 0.f};
    }

    // prologue: quarter 0 in flight while hist is zeroed
    ISSUE_Q(0, Xb0);
    for (int i = tid; i < HSZ; i += TPB) hist[i] = 0;
    __syncthreads();   // q0 ready

#pragma unroll
    for (int ks = 0; ks < 4; ++ks) {
        const float* curb = (ks & 1) ? Xb1 : Xb0;
        if (ks < 3) {
            if ((ks + 1) & 1) ISSUE_Q(ks + 1, Xb1);
            else              ISSUE_Q(ks + 1, Xb0);
        }

        // B-frags for this quarter from LDS (ds_read_b32, 4-way alias ~1.6x)
        bf16x8 bfrag[2];
#pragma unroll
        for (int lt = 0; lt < 2; ++lt) {
            const int ll = wave * 32 + lt * 16 + nn;
            float xf[8];
#pragma unroll
            for (int j = 0; j < 8; ++j)
                xf[j] = curb[(quad * 8 + j) * LT_ + ll];
            unsigned int u[4];
#pragma unroll
            for (int jp = 0; jp < 4; ++jp) {
                __hip_bfloat162 h2 = __float22bfloat162_rn(
                    make_float2(xf[2 * jp], xf[2 * jp + 1]));
                __builtin_memcpy(&u[jp], &h2, 4);
            }
            __builtin_memcpy(&bfrag[lt], u, 16);
        }

        // 14 MFMAs on this quarter; A-frags from global Wf (L1-hot)
#pragma unroll
        for (int pt = 0; pt < NPT; ++pt) {
            const bf16x8 af = *(const bf16x8*)(Wf + ((size_t)(pt * 4 + ks) * 64 + lane) * 8);
            acc[pt][0] = __builtin_amdgcn_mfma_f32_16x16x32_bf16(af, bfrag[0], acc[pt][0], 0, 0, 0);
            acc[pt][1] = __builtin_amdgcn_mfma_f32_16x16x32_bf16(af, bfrag[1], acc[pt][1], 0, 0, 0);
        }
        __syncthreads();   // drains DMA(ks+1); also guards buffer reuse at ks+2
    }

    // ---- bucket: D row = quad*4 + r -> p = pt*16 + quad*4 + r (skip pad rows)
#pragma unroll
    for (int pt = 0; pt < NPT; ++pt)
#pragma unroll
        for (int r = 0; r < 4; ++r) {
            const int p = pt * 16 + quad * 4 + r;
            if (p < P_) {
                const float mn = mn_c[p], invd = invd_c[p];
#pragma unroll
                for (int lt = 0; lt < 2; ++lt) {
                    const float t = (acc[pt][lt][r] - mn) * invd;
                    int k = 0;
                    if (t > 0.f) { const int ki = (int)t; k = (ki > 20) ? 20 : ki; }
                    atomicAdd(&hist[p * NBIN + k], 1);
                }
            }
        }
    __syncthreads();

    // ---- epilogue: prefix-sum histogram -> exact fp32 atomic accumulation
    for (int i = tid; i < P_ * Q_; i += TPB) {
        const int p  = i / Q_;
        const int qi = i - p * Q_;
        int s = 0;
        for (int k = 0; k <= qi; ++k) s += hist[p * NBIN + k];
        atomicAdd(&out[((size_t)b * P_ + p) * Q_ + qi], (float)s * (1.0f / (float)L_));
    }
#undef ISSUE_Q
}

extern "C" void kernel_launch(void* const* d_in, const int* in_sizes, int n_in,
                              void* d_out, int out_size, void* d_ws, size_t ws_size,
                              hipStream_t stream) {
    const float* X  = (const float*)d_in[0];
    const float* W  = (const float*)d_in[1];
    const float* mn = (const float*)d_in[2];
    const float* mx = (const float*)d_in[3];
    float* out = (float*)d_out;
    unsigned short* Wf = (unsigned short*)d_ws;   // 28672 B

    hipMemsetAsync(out, 0, (size_t)out_size * sizeof(float), stream);
    prep_kernel<<<8, 256, 0, stream>>>(W, mn, mx, Wf);

    dim3 grid(L_ / LT_, B_);
    radon_pipe_kernel<<<grid, dim3(TPB), 0, stream>>>(X, Wf, out);
}